// Round 13
// baseline (613.084 us; speedup 1.0000x reference)
//
#include <hip/hip_runtime.h>
#include <math.h>

#define BATCH 256
#define T 1024
#define IN 19
#define H 128

typedef _Float16 h2 __attribute__((ext_vector_type(2)));

// tanh via v_exp_f32: tanh(x)=sign(x)*(1-2/(exp(2|x|)+1)); exact to ~1e-7.
__device__ __forceinline__ float fast_tanh(float x) {
    float ax = fabsf(x);
    float e  = __expf(2.0f * ax);
    float r  = 1.0f - 2.0f / (e + 1.0f);
    return copysignf(r, x);
}

// DPP cross-lane move (VALU-only, no LDS pipe).
template <int CTRL>
__device__ __forceinline__ float dppf(float v) {
    return __int_as_float(__builtin_amdgcn_update_dpp(
        0, __float_as_int(v), CTRL, 0xF, 0xF, true));
}
#define XOR1 0xB1   // quad_perm [1,0,3,2]  : lane ^= 1
#define XOR2 0x4E   // quad_perm [2,3,0,1]  : lane ^= 2
#define XOR8 0x128  // row_ror:8            : lane ^= 8 (within 16-lane row)

__device__ __forceinline__ h2 toh2(unsigned int u) {
    union { unsigned int i; h2 h; } c; c.i = u; return c.h;
}
// v_dot2_f32_f16: d = a.x*b.x + a.y*b.y + c, f32 accumulate (products exact;
// only the f16 INPUT roundings contribute error).
__device__ __forceinline__ float fdot2(h2 a, h2 b, float c) {
    return __builtin_amdgcn_fdot2(a, b, c, false);
}

// Lightweight barrier: waits LDS only (NO vmcnt drain).
__device__ __forceinline__ void sync_fast() {
    asm volatile("s_waitcnt lgkmcnt(0)" ::: "memory");
    __builtin_amdgcn_s_barrier();
    __builtin_amdgcn_s_barrier();  // (placeholder removed below)
}

// NOTE: the double-barrier above would break interval accounting — define the
// real one; (kept single, see sync() below).
__device__ __forceinline__ void sync() {
    asm volatile("s_waitcnt lgkmcnt(0)" ::: "memory");
    __builtin_amdgcn_s_barrier();
    asm volatile("" ::: "memory");
}

// f16 ring offset for hidden unit u: 16-elem slices padded to 24 (48 B:
// 16B-aligned; slice word-bases {0,12,24,4,16,28,8,20} mod 32 -> both b128
// reads per lane hit 32 distinct banks across the 8 slices. Verified.)
__device__ __forceinline__ int uoff16(int u) { return (u >> 4) * 24 + (u & 15); }

// ---------------------------------------------------------------------------
// R12 structure (best-measured: 546us dispatch), with the three matvec
// datapaths converted to f16 v_dot2_f32_f16:
//   - h0/h1 rings stored as _Float16 (LDS traffic 36->18 KB/step)
//   - Whh0/Wih1/Whh1 fragments packed h2 in regs (dot issue halved)
//   - proj path, Bring, biases, tanh, output: all f32 (precision anchors)
// Error budget: f16 input rounding -> per-step 128-term random-walk ~1e-4,
// recurrence contraction rho~0.6 -> steady ~1e-3; absmax predicted 5e-3..1e-2
// vs threshold 1.65e-2 (current floor 2^-8 = bf16 output quantization).
// Barrier schedule byte-identical to R12: all groups execute 1027 barriers.
// ---------------------------------------------------------------------------
__global__ __launch_bounds__(512)
__attribute__((amdgpu_waves_per_eu(2, 2)))
void fused_rnn(const float* __restrict__ x,      // [B,T,IN]
               const float* __restrict__ Wih0,   // [H,IN]
               const float* __restrict__ Whh0,   // [H,H]
               const float* __restrict__ bih0,
               const float* __restrict__ bhh0,
               const float* __restrict__ Wih1,   // [H,H]
               const float* __restrict__ Whh1,   // [H,H]
               const float* __restrict__ bih1,
               const float* __restrict__ bhh1,
               float* __restrict__ out) {        // [B,T,H]
    const int b   = blockIdx.x;
    const int tid = threadIdx.x;

    __shared__ __align__(16) _Float16 h0r[4][8 * 24];
    __shared__ __align__(16) _Float16 h1r[4][8 * 24];
    __shared__ __align__(16) float Bring[4][H];
    __shared__ __align__(16) float projring[4][H];   // proj0 for step k at [k&3]
    // x chunks: 8 steps x 19 floats, stride 20. Chunk c holds rows 8c+1..8c+8.
    __shared__ __align__(16) float xbuf[2][8 * 20];

    if (tid < 128) {
        // =================== S0 (pure recurrence) ===================
        __builtin_amdgcn_s_setprio(1);
        const bool b0 = tid & 1, b1 = tid & 2, b2 = tid & 8;
        const int s    = (tid & 3) | ((tid & 8) >> 1);          // slice 0..7
        const int G    = (tid >> 4) * 2 + ((tid >> 2) & 1);     // group 0..15
        const int ub   = G * 8;
        const int ufin = ub + (b0 ? 4 : 0) + (b1 ? 2 : 0) + (b2 ? 1 : 0);

        h2 wh[8][8];
#pragma unroll
        for (int u = 0; u < 8; ++u) {
            const float* wr = Whh0 + (size_t)(ub + u) * H + s * 16;
#pragma unroll
            for (int k = 0; k < 8; ++k) {
                h2 t; t[0] = (_Float16)wr[2 * k]; t[1] = (_Float16)wr[2 * k + 1];
                wh[u][k] = t;
            }
        }
        // prologue: proj_0 self-computed (P's ring starts at proj_1)
        {
            const float* wr = Wih0 + ufin * IN;
            const float* xr = x + (size_t)b * T * IN;   // row 0
            float acc = bih0[ufin] + bhh0[ufin];
#pragma unroll
            for (int f = 0; f < IN; ++f) acc = fmaf(xr[f], wr[f], acc);
            projring[0][ufin] = acc;
        }
        h0r[3][uoff16(ufin)] = (_Float16)0.0f;   // h0_{-1}
        sync();                                   // init barrier

        const int so = s * 24;
        const int wo = uoff16(ufin);
        for (int ko = 0; ko < T; ko += 8) {
#pragma unroll
            for (int j = 0; j < 8; ++j) {
                const _Float16* hrow = &h0r[(j + 3) & 3][so];
                float pcur = projring[j & 3][ufin];
                uint4 q0 = *(const uint4*)(hrow);
                uint4 q1 = *(const uint4*)(hrow + 8);
                h2 hp[8];
                hp[0] = toh2(q0.x); hp[1] = toh2(q0.y);
                hp[2] = toh2(q0.z); hp[3] = toh2(q0.w);
                hp[4] = toh2(q1.x); hp[5] = toh2(q1.y);
                hp[6] = toh2(q1.z); hp[7] = toh2(q1.w);
                float d0=0,d1=0,d2=0,d3=0,d4=0,d5=0,d6=0,d7=0;
#pragma unroll
                for (int k = 0; k < 8; ++k) {
                    d0 = fdot2(hp[k], wh[0][k], d0);
                    d1 = fdot2(hp[k], wh[1][k], d1);
                    d2 = fdot2(hp[k], wh[2][k], d2);
                    d3 = fdot2(hp[k], wh[3][k], d3);
                    d4 = fdot2(hp[k], wh[4][k], d4);
                    d5 = fdot2(hp[k], wh[5][k], d5);
                    d6 = fdot2(hp[k], wh[6][k], d6);
                    d7 = fdot2(hp[k], wh[7][k], d7);
                }
                float e0 = (b0 ? d4 : d0) + dppf<XOR1>(b0 ? d0 : d4);
                float e1 = (b0 ? d5 : d1) + dppf<XOR1>(b0 ? d1 : d5);
                float e2 = (b0 ? d6 : d2) + dppf<XOR1>(b0 ? d2 : d6);
                float e3 = (b0 ? d7 : d3) + dppf<XOR1>(b0 ? d3 : d7);
                float g0 = (b1 ? e2 : e0) + dppf<XOR2>(b1 ? e0 : e2);
                float g1 = (b1 ? e3 : e1) + dppf<XOR2>(b1 ? e1 : e3);
                float f  = (b2 ? g1 : g0) + dppf<XOR8>(b2 ? g0 : g1);
                h0r[j & 3][wo] = (_Float16)fast_tanh(pcur + f);
                sync();
            }
        }
        sync();   // interval 1024
        sync();   // interval 1025
    } else if (tid < 384) {
        // =================== P (B-projection + layer-0 input projection) ====
        const int p  = tid - 128;
        const bool b0 = p & 1, b1 = p & 2;
        const int s    = (p & 3) | ((p & 8) >> 1);            // slice 0..7
        const int Gp   = (p >> 4) * 2 + ((p >> 2) & 1);       // group 0..31
        const int ub   = Gp * 4;
        const int ufin = ub + (b0 ? 2 : 0) + (b1 ? 1 : 0);

        h2 wph[4][8];
#pragma unroll
        for (int u = 0; u < 4; ++u) {
            const float* wr = Wih1 + (size_t)(ub + u) * H + s * 16;
#pragma unroll
            for (int k = 0; k < 8; ++k) {
                h2 t; t[0] = (_Float16)wr[2 * k]; t[1] = (_Float16)wr[2 * k + 1];
                wph[u][k] = t;
            }
        }
        const float biasP = bih1[ufin] + bhh1[ufin];

        // ---- proj duty: waves 4-5 (p>=128), unit = p-128 ----
        const bool hasProj = (p >= 128);
        const int pu = p - 128;                        // proj unit 0..127
        float wIP[20];
        float biasPr = 0.0f;
        const float* xsrc = x + (size_t)b * T * IN + IN;   // row 1 base
        const int idx0  = pu;
        const int idx1  = pu + 128;
        const bool v1   = hasProj && (pu < 24);
        const int slot0 = hasProj ? ((idx0 / IN) * 20 + idx0 % IN) : 0;
        const int slot1 = hasProj ? ((idx1 / IN) * 20 + idx1 % IN) : 0;
        const int XMAX  = (T - 1) * IN - 1;                // last elem rel to xsrc
        float xr0 = 0.0f, xr1 = 0.0f;

        if (hasProj) {
            const float* wr = Wih0 + (size_t)pu * IN;
#pragma unroll
            for (int f = 0; f < IN; ++f) wIP[f] = wr[f];
            wIP[19] = 0.0f;
            biasPr = bih0[pu] + bhh0[pu];
            if (pu < 8) { xbuf[0][pu * 20 + 19] = 0.0f; xbuf[1][pu * 20 + 19] = 0.0f; }
            xbuf[0][slot0] = xsrc[idx0];
            if (v1) xbuf[0][slot1] = xsrc[idx1];
            xr0 = xsrc[152 + idx0];
            if (v1) xr1 = xsrc[152 + idx1];
        }
        sync();   // init barrier

        const int so = s * 24;
        for (int ko = 0; ko < T; ko += 8) {
            const int cb = (ko >> 3) & 1;
#pragma unroll
            for (int j = 0; j < 8; ++j) {
                // ---- B_{k-1}: dot over h0_{k-1} (slot (j+3)&3) ----
                const _Float16* hrow = &h0r[(j + 3) & 3][so];
                uint4 q0 = *(const uint4*)(hrow);
                uint4 q1 = *(const uint4*)(hrow + 8);
                h2 hp[8];
                hp[0] = toh2(q0.x); hp[1] = toh2(q0.y);
                hp[2] = toh2(q0.z); hp[3] = toh2(q0.w);
                hp[4] = toh2(q1.x); hp[5] = toh2(q1.y);
                hp[6] = toh2(q1.z); hp[7] = toh2(q1.w);
                float d0=0,d1=0,d2=0,d3=0;
#pragma unroll
                for (int k = 0; k < 8; ++k) {
                    d0 = fdot2(hp[k], wph[0][k], d0);
                    d1 = fdot2(hp[k], wph[1][k], d1);
                    d2 = fdot2(hp[k], wph[2][k], d2);
                    d3 = fdot2(hp[k], wph[3][k], d3);
                }
                float e0 = (b0 ? d2 : d0) + dppf<XOR1>(b0 ? d0 : d2);
                float e1 = (b0 ? d3 : d1) + dppf<XOR1>(b0 ? d1 : d3);
                float g  = (b1 ? e1 : e0) + dppf<XOR2>(b1 ? e0 : e1);
                g += dppf<XOR8>(g);
                if (!(p & 8)) Bring[(j + 3) & 3][ufin] = g + biasP;
                // ---- proj0_{k+1} from x row j of current chunk (f32) ----
                if (hasProj) {
                    const float* xp = &xbuf[cb][j * 20];
                    float4 xv0 = *(const float4*)&xp[0];
                    float4 xv1 = *(const float4*)&xp[4];
                    float4 xv2 = *(const float4*)&xp[8];
                    float4 xv3 = *(const float4*)&xp[12];
                    float4 xv4 = *(const float4*)&xp[16];   // .w = pad
                    float p0 = biasPr, p1 = 0.0f;
                    p0 = fmaf(xv0.x, wIP[0],  p0); p1 = fmaf(xv0.y, wIP[1],  p1);
                    p0 = fmaf(xv0.z, wIP[2],  p0); p1 = fmaf(xv0.w, wIP[3],  p1);
                    p0 = fmaf(xv1.x, wIP[4],  p0); p1 = fmaf(xv1.y, wIP[5],  p1);
                    p0 = fmaf(xv1.z, wIP[6],  p0); p1 = fmaf(xv1.w, wIP[7],  p1);
                    p0 = fmaf(xv2.x, wIP[8],  p0); p1 = fmaf(xv2.y, wIP[9],  p1);
                    p0 = fmaf(xv2.z, wIP[10], p0); p1 = fmaf(xv2.w, wIP[11], p1);
                    p0 = fmaf(xv3.x, wIP[12], p0); p1 = fmaf(xv3.y, wIP[13], p1);
                    p0 = fmaf(xv3.z, wIP[14], p0); p1 = fmaf(xv3.w, wIP[15], p1);
                    p0 = fmaf(xv4.x, wIP[16], p0); p1 = fmaf(xv4.y, wIP[17], p1);
                    p0 = fmaf(xv4.z, wIP[18], p0); p1 = fmaf(xv4.w, wIP[19], p1);
                    projring[(j + 1) & 3][pu] = p0 + p1;
                    if (j == 7) {
                        // publish chunk c+1 (pre-barrier), fetch chunk c+2
                        float* xd = xbuf[cb ^ 1];
                        xd[slot0] = xr0;
                        if (v1) xd[slot1] = xr1;
                        const int c2 = (ko >> 3) + 2;
                        int o0 = 152 * c2 + idx0; o0 = o0 > XMAX ? XMAX : o0;
                        int o1 = 152 * c2 + idx1; o1 = o1 > XMAX ? XMAX : o1;
                        xr0 = xsrc[o0];
                        if (v1) xr1 = xsrc[o1];
                    }
                }
                sync();
            }
        }
        // ---- epilogue (interval 1024): B_1023 from h0_1023 (slot 3) ----
        {
            const _Float16* hrow = &h0r[3][so];
            uint4 q0 = *(const uint4*)(hrow);
            uint4 q1 = *(const uint4*)(hrow + 8);
            h2 hp[8];
            hp[0] = toh2(q0.x); hp[1] = toh2(q0.y);
            hp[2] = toh2(q0.z); hp[3] = toh2(q0.w);
            hp[4] = toh2(q1.x); hp[5] = toh2(q1.y);
            hp[6] = toh2(q1.z); hp[7] = toh2(q1.w);
            float d0=0,d1=0,d2=0,d3=0;
#pragma unroll
            for (int k = 0; k < 8; ++k) {
                d0 = fdot2(hp[k], wph[0][k], d0);
                d1 = fdot2(hp[k], wph[1][k], d1);
                d2 = fdot2(hp[k], wph[2][k], d2);
                d3 = fdot2(hp[k], wph[3][k], d3);
            }
            float e0 = (b0 ? d2 : d0) + dppf<XOR1>(b0 ? d0 : d2);
            float e1 = (b0 ? d3 : d1) + dppf<XOR1>(b0 ? d1 : d3);
            float g  = (b1 ? e1 : e0) + dppf<XOR2>(b1 ? e0 : e1);
            g += dppf<XOR8>(g);
            if (!(p & 8)) Bring[3][ufin] = g + biasP;
        }
        sync();   // interval 1024
        sync();   // interval 1025
    } else {
        // =================== S1 ===================
        __builtin_amdgcn_s_setprio(1);
        const int w  = tid - 384;
        const bool b0 = w & 1, b1 = w & 2, b2 = w & 8;
        const int s    = (w & 3) | ((w & 8) >> 1);
        const int G    = (w >> 4) * 2 + ((w >> 2) & 1);
        const int ub   = G * 8;
        const int ufin = ub + (b0 ? 4 : 0) + (b1 ? 2 : 0) + (b2 ? 1 : 0);

        h2 wh[8][8];
#pragma unroll
        for (int u = 0; u < 8; ++u) {
            const float* wr = Whh1 + (size_t)(ub + u) * H + s * 16;
#pragma unroll
            for (int k = 0; k < 8; ++k) {
                h2 t; t[0] = (_Float16)wr[2 * k]; t[1] = (_Float16)wr[2 * k + 1];
                wh[u][k] = t;
            }
        }
        float* orow = out + (size_t)b * T * H + ufin;
        float sbuf[8];

        h1r[3][uoff16(ufin)] = (_Float16)0.0f;   // h1_{-1}
        sync();   // init barrier
        sync();   // interval 0
        sync();   // interval 1

        const int so = s * 24;
        const int wo = uoff16(ufin);
        for (int ko = 2; ko < 1026; ko += 8) {
#pragma unroll
            for (int j = 0; j < 8; ++j) {
                // ko%8==2: h1_{t-1} slot -> (j+3)&3 ; B_{k-2} slot -> j&3
                const _Float16* hrow = &h1r[(j + 3) & 3][so];
                float Bg = Bring[j & 3][ufin];
                uint4 q0 = *(const uint4*)(hrow);
                uint4 q1 = *(const uint4*)(hrow + 8);
                h2 hp[8];
                hp[0] = toh2(q0.x); hp[1] = toh2(q0.y);
                hp[2] = toh2(q0.z); hp[3] = toh2(q0.w);
                hp[4] = toh2(q1.x); hp[5] = toh2(q1.y);
                hp[6] = toh2(q1.z); hp[7] = toh2(q1.w);
                float d0=0,d1=0,d2=0,d3=0,d4=0,d5=0,d6=0,d7=0;
#pragma unroll
                for (int k = 0; k < 8; ++k) {
                    d0 = fdot2(hp[k], wh[0][k], d0);
                    d1 = fdot2(hp[k], wh[1][k], d1);
                    d2 = fdot2(hp[k], wh[2][k], d2);
                    d3 = fdot2(hp[k], wh[3][k], d3);
                    d4 = fdot2(hp[k], wh[4][k], d4);
                    d5 = fdot2(hp[k], wh[5][k], d5);
                    d6 = fdot2(hp[k], wh[6][k], d6);
                    d7 = fdot2(hp[k], wh[7][k], d7);
                }
                float e0 = (b0 ? d4 : d0) + dppf<XOR1>(b0 ? d0 : d4);
                float e1 = (b0 ? d5 : d1) + dppf<XOR1>(b0 ? d1 : d5);
                float e2 = (b0 ? d6 : d2) + dppf<XOR1>(b0 ? d2 : d6);
                float e3 = (b0 ? d7 : d3) + dppf<XOR1>(b0 ? d3 : d7);
                float g0 = (b1 ? e2 : e0) + dppf<XOR2>(b1 ? e0 : e2);
                float g1 = (b1 ? e3 : e1) + dppf<XOR2>(b1 ? e1 : e3);
                float f  = (b2 ? g1 : g0) + dppf<XOR8>(b2 ? g0 : g1);
                float h1v = fast_tanh(Bg + f);
                h1r[j & 3][wo] = (_Float16)h1v;
                sbuf[j] = h1v;
                if (j == 7) {                  // burst-write t = ko-2 .. ko+5
                    const int t0 = ko - 2;
#pragma unroll
                    for (int i = 0; i < 8; ++i)
                        orow[(size_t)(t0 + i) * H] = sbuf[i];
                }
                sync();
            }
        }
        // no trailing barriers needed for S1 (last interval is 1025)
    }
}

// ---------------------------------------------------------------------------
extern "C" void kernel_launch(void* const* d_in, const int* in_sizes, int n_in,
                              void* d_out, int out_size, void* d_ws, size_t ws_size,
                              hipStream_t stream) {
    const float* x     = (const float*)d_in[0];
    const float* W_ih0 = (const float*)d_in[1];
    const float* W_hh0 = (const float*)d_in[2];
    const float* b_ih0 = (const float*)d_in[3];
    const float* b_hh0 = (const float*)d_in[4];
    const float* W_ih1 = (const float*)d_in[5];
    const float* W_hh1 = (const float*)d_in[6];
    const float* b_ih1 = (const float*)d_in[7];
    const float* b_hh1 = (const float*)d_in[8];

    float* out = (float*)d_out;

    fused_rnn<<<BATCH, 512, 0, stream>>>(x, W_ih0, W_hh0, b_ih0, b_hh0,
                                         W_ih1, W_hh1, b_ih1, b_hh1, out);
}